// Round 6
// baseline (643.989 us; speedup 1.0000x reference)
//
#include <hip/hip_runtime.h>
#include <hip/hip_fp16.h>
#include <stdint.h>

// SymmetricQuantLinear: out[m,n] = scale[n] * sum_k x[m,k] * (nib(k,n) - 8)
//   x: f32 [M][K] (fp16 values upconverted by harness; cvt to fp16 in staging)
//   packed: int32 [K/2][N] (1 byte/int: lo nibble = even k, hi = odd k)
//   scale: f32 [N].  Out: f32 [M][N].
// Round 6: 256x256 tile, BK=32, 8 waves (2Mx4N), mfma_f32_16x16x32_f16,
// packed fp16-domain dequant (v_pk_add_f16), XCD-aware block swizzle.

#define M_DIM 4096
#define K_DIM 4096
#define N_DIM 11008

typedef __attribute__((ext_vector_type(8))) _Float16 f16x8;
typedef __attribute__((ext_vector_type(2))) _Float16 h2;
typedef __attribute__((ext_vector_type(4))) float f32x4;

__device__ __forceinline__ unsigned pack_f16_pair(float lo, float hi) {
    // v_cvt_pkrtz_f16_f32 — exact for fp16-origin f32 values.
    return __builtin_bit_cast(unsigned, __builtin_amdgcn_cvt_pkrtz(lo, hi));
}

__device__ __forceinline__ unsigned dq_pair(unsigned v) {
    // byte v = (hi<<4)|lo  ->  packed fp16 (lo-8, hi-8), exact.
    // (1024+nib) via exponent trick, then packed subtract 1032.
    unsigned c = (v & 0xFu) | ((v << 12) & 0x000F0000u) | 0x64006400u;
    h2 r = __builtin_bit_cast(h2, c) + __builtin_bit_cast(h2, 0xE408E408u); // -1032,-1032
    return __builtin_bit_cast(unsigned, r);
}

__global__ void __launch_bounds__(512) qgemm_kernel(
    const float* __restrict__ X,            // f32 [M][K]
    const int*   __restrict__ WP,           // [K/2][N]
    const float* __restrict__ WS,           // [N]
    float*       __restrict__ Out)          // f32 [M][N]
{
    __shared__ unsigned short As[256 * 40];      // [m][k] fp16, row stride 40 (pad 8)
    __shared__ unsigned short Bs[256 * 40];      // [n][k] fp16, row stride 40 (pad 8)

    const int t = threadIdx.x;
    const int w = t >> 6;        // wave 0..7
    const int l = t & 63;        // lane

    // XCD-aware swizzle: 688 blocks, 688 % 8 == 0 -> xcd gets 86 contiguous tiles
    const int bid = blockIdx.x;
    const int wg  = (bid & 7) * 86 + (bid >> 3);
    const int by  = wg / 43;                 // M-tile 0..15
    const int bx  = wg - by * 43;            // N-tile 0..42
    const int bm0 = by * 256;
    const int bn0 = bx * 256;

    const int wr = w >> 2;       // wave row (0..1) -> 128 out rows
    const int wc = w & 3;        // wave col (0..3) -> 64 out cols

    f32x4 acc[8][4];
#pragma unroll
    for (int i = 0; i < 8; ++i)
#pragma unroll
        for (int j = 0; j < 4; ++j)
            acc[i][j] = (f32x4){0.f, 0.f, 0.f, 0.f};

    // ---- A staging: thread t covers rows {t>>2, 128+(t>>2)}, k-off (t&3)*8 ----
    const int ar = t >> 2;              // 0..127
    const int ak = (t & 3) * 8;         // 0,8,16,24
    const float* xg = X + (size_t)(bm0 + ar) * K_DIM + ak;

    // ---- B staging: thread covers cols nl, nl+1; packed rows rg*4+rr ----
    const int cp = t & 127;             // col-pair 0..127
    const int nl = 2 * cp;
    const int rg = t >> 7;              // 0..3 -> k-local rg*8
    const int* wp0 = WP + (size_t)(rg * 4) * N_DIM + (bn0 + nl);

    const int NT = K_DIM / 32;          // 128 K-steps

    // prefetch kt=0
    float4 a0lo = *(const float4*)(xg);
    float4 a0hi = *(const float4*)(xg + 4);
    float4 a1lo = *(const float4*)(xg + (size_t)128 * K_DIM);
    float4 a1hi = *(const float4*)(xg + (size_t)128 * K_DIM + 4);
    int2 pv[4];
#pragma unroll
    for (int rr = 0; rr < 4; ++rr)
        pv[rr] = *(const int2*)(wp0 + (size_t)rr * N_DIM);

    const int lq = l >> 4;   // k-quarter 0..3
    const int lr = l & 15;

    for (int kt = 0; kt < NT; ++kt) {
        // ---- convert + write staged A (f32 -> fp16, exact) ----
        uint4 av0 = make_uint4(pack_f16_pair(a0lo.x, a0lo.y),
                               pack_f16_pair(a0lo.z, a0lo.w),
                               pack_f16_pair(a0hi.x, a0hi.y),
                               pack_f16_pair(a0hi.z, a0hi.w));
        uint4 av1 = make_uint4(pack_f16_pair(a1lo.x, a1lo.y),
                               pack_f16_pair(a1lo.z, a1lo.w),
                               pack_f16_pair(a1hi.x, a1hi.y),
                               pack_f16_pair(a1hi.z, a1hi.w));
        *(uint4*)(&As[(size_t)ar * 40 + ak])         = av0;
        *(uint4*)(&As[(size_t)(128 + ar) * 40 + ak]) = av1;

        // ---- dequant + write staged B (packed fp16, exact ints) ----
        uint4 blo = make_uint4(dq_pair((unsigned)pv[0].x), dq_pair((unsigned)pv[1].x),
                               dq_pair((unsigned)pv[2].x), dq_pair((unsigned)pv[3].x));
        uint4 bhi = make_uint4(dq_pair((unsigned)pv[0].y), dq_pair((unsigned)pv[1].y),
                               dq_pair((unsigned)pv[2].y), dq_pair((unsigned)pv[3].y));
        *(uint4*)(&Bs[(size_t)nl * 40 + rg * 8])       = blo;
        *(uint4*)(&Bs[(size_t)(nl + 1) * 40 + rg * 8]) = bhi;

        __syncthreads();   // As/Bs ready

        // ---- prefetch kt+1 (latency hides under MFMA) ----
        if (kt + 1 < NT) {
            const int k1 = (kt + 1) * 32;
            a0lo = *(const float4*)(xg + k1);
            a0hi = *(const float4*)(xg + k1 + 4);
            a1lo = *(const float4*)(xg + (size_t)128 * K_DIM + k1);
            a1hi = *(const float4*)(xg + (size_t)128 * K_DIM + k1 + 4);
#pragma unroll
            for (int rr = 0; rr < 4; ++rr)
                pv[rr] = *(const int2*)(wp0 + ((size_t)(kt + 1) * 16 + rr) * N_DIM);
        }

        // ---- fragments + MFMA ----
        f16x8 af[8], bfr[4];
#pragma unroll
        for (int mi = 0; mi < 8; ++mi) {
            const int row = wr * 128 + mi * 16 + lr;
            af[mi] = *(const f16x8*)&As[(size_t)row * 40 + lq * 8];
        }
#pragma unroll
        for (int ni = 0; ni < 4; ++ni) {
            const int col = wc * 64 + ni * 16 + lr;
            bfr[ni] = *(const f16x8*)&Bs[(size_t)col * 40 + lq * 8];
        }
#pragma unroll
        for (int mi = 0; mi < 8; ++mi)
#pragma unroll
            for (int ni = 0; ni < 4; ++ni)
                acc[mi][ni] = __builtin_amdgcn_mfma_f32_16x16x32_f16(
                    af[mi], bfr[ni], acc[mi][ni], 0, 0, 0);

        __syncthreads();   // frag reads done; LDS free for next stage
    }

    // ---- epilogue: per-column scale, f32 store ----
#pragma unroll
    for (int ni = 0; ni < 4; ++ni) {
        const int col = bn0 + wc * 64 + ni * 16 + lr;
        const float s = WS[col];
#pragma unroll
        for (int mi = 0; mi < 8; ++mi) {
            const int row = bm0 + wr * 128 + mi * 16 + lq * 4;
#pragma unroll
            for (int i = 0; i < 4; ++i) {
                Out[(size_t)(row + i) * N_DIM + col] = acc[mi][ni][i] * s;
            }
        }
    }
}

extern "C" void kernel_launch(void* const* d_in, const int* in_sizes, int n_in,
                              void* d_out, int out_size, void* d_ws, size_t ws_size,
                              hipStream_t stream) {
    const float* X  = (const float*)d_in[0];
    const int*   WP = (const int*)d_in[1];
    const float* WS = (const float*)d_in[2];
    float*       Out = (float*)d_out;

    dim3 grid((N_DIM / 256) * (M_DIM / 256));   // 43 * 16 = 688
    qgemm_kernel<<<grid, 512, 0, stream>>>(X, WP, WS, Out);
}

// Round 7
// 567.416 us; speedup vs baseline: 1.1349x; 1.1349x over previous
//
#include <hip/hip_runtime.h>
#include <hip/hip_fp16.h>
#include <stdint.h>

// SymmetricQuantLinear: out[m,n] = scale[n] * sum_k x[m,k] * (nib(k,n) - 8)
//   x: f32 [M][K] (fp16 values; cvt to fp16 in staging — exact)
//   packed: int32 [K/2][N] (1 byte/int: lo nibble = even k, hi = odd k)
//   scale: f32 [N].  Out: f32 [M][N].
// Round 7: 128x128 tile, 4 waves, BK=32, DOUBLE-BUFFERED LDS with ONE
// barrier per K-step, 2-deep ping-pong register prefetch (static unroll x2),
// packed fp16-domain dequant, XCD-aware swizzle (2752 % 8 == 0).

#define M_DIM 4096
#define K_DIM 4096
#define N_DIM 11008

typedef __attribute__((ext_vector_type(8))) _Float16 f16x8;
typedef __attribute__((ext_vector_type(2))) _Float16 h2;
typedef __attribute__((ext_vector_type(4))) float f32x4;

__device__ __forceinline__ unsigned pack_f16_pair(float lo, float hi) {
    return __builtin_bit_cast(unsigned, __builtin_amdgcn_cvt_pkrtz(lo, hi));
}

__device__ __forceinline__ unsigned dq_pair(unsigned v) {
    // byte v = (hi<<4)|lo  ->  packed fp16 (lo-8, hi-8), exact.
    unsigned c = (v & 0xFu) | ((v << 12) & 0x000F0000u) | 0x64006400u;
    h2 r = __builtin_bit_cast(h2, c) + __builtin_bit_cast(h2, 0xE408E408u); // -=1032
    return __builtin_bit_cast(unsigned, r);
}

__global__ void __launch_bounds__(256) qgemm_kernel(
    const float* __restrict__ X,            // f32 [M][K]
    const int*   __restrict__ WP,           // [K/2][N]
    const float* __restrict__ WS,           // [N]
    float*       __restrict__ Out)          // f32 [M][N]
{
    __shared__ unsigned short As[2][128 * 40];   // [m][k] fp16, stride 40
    __shared__ unsigned short Bs[2][128 * 40];   // [n][k] fp16, stride 40

    const int t = threadIdx.x;
    const int w = t >> 6;        // wave 0..3
    const int l = t & 63;

    // XCD swizzle: 2752 blocks, 2752/8 = 344 contiguous wgs per XCD.
    const int bid = blockIdx.x;
    const int wg  = (bid & 7) * 344 + (bid >> 3);
    const int by  = wg / 86;                 // M-tile 0..31
    const int bx  = wg - by * 86;            // N-tile 0..85
    const int bm0 = by * 128;
    const int bn0 = bx * 128;

    const int wr = w >> 1;       // 64-row half
    const int wc = w & 1;        // 64-col half

    f32x4 acc[4][4];
#pragma unroll
    for (int i = 0; i < 4; ++i)
#pragma unroll
        for (int j = 0; j < 4; ++j)
            acc[i][j] = (f32x4){0.f, 0.f, 0.f, 0.f};

    // A staging: thread t covers rows {t>>2, 64+(t>>2)}, k-off (t&3)*8
    const int ar = t >> 2;
    const int ak = (t & 3) * 8;
    const float* xg = X + (size_t)(bm0 + ar) * K_DIM + ak;

    // B staging: cols nl, nl+1; packed rows rg*4+rr -> k-local rg*8 + 2rr(+1)
    const int nl = 2 * l;
    const int rg = w;
    const int* wp0 = WP + (size_t)(rg * 4) * N_DIM + (bn0 + nl);

    const int lq = l >> 4;
    const int lr = l & 15;

    const int NT = K_DIM / 32;   // 128

    // ping-pong register sets
    float4 sA0a, sA0b, sA1a, sA1b; int2 sP0[4];   // set 0
    float4 tA0a, tA0b, tA1a, tA1b; int2 tP0[4];   // set 1

#define LOAD_SET(Aa, Ab, Ba, Bb, P, kt) do {                                  \
    const int _k = (kt) * 32;                                                 \
    Aa = *(const float4*)(xg + _k);                                           \
    Ab = *(const float4*)(xg + _k + 4);                                       \
    Ba = *(const float4*)(xg + (size_t)64 * K_DIM + _k);                      \
    Bb = *(const float4*)(xg + (size_t)64 * K_DIM + _k + 4);                  \
    P[0] = *(const int2*)(wp0 + ((size_t)(kt) * 16 + 0) * N_DIM);             \
    P[1] = *(const int2*)(wp0 + ((size_t)(kt) * 16 + 1) * N_DIM);             \
    P[2] = *(const int2*)(wp0 + ((size_t)(kt) * 16 + 2) * N_DIM);             \
    P[3] = *(const int2*)(wp0 + ((size_t)(kt) * 16 + 3) * N_DIM);             \
} while (0)

#define WRITE_SET(Aa, Ab, Ba, Bb, P, buf) do {                                \
    uint4 _av0 = make_uint4(pack_f16_pair(Aa.x, Aa.y), pack_f16_pair(Aa.z, Aa.w), \
                            pack_f16_pair(Ab.x, Ab.y), pack_f16_pair(Ab.z, Ab.w)); \
    uint4 _av1 = make_uint4(pack_f16_pair(Ba.x, Ba.y), pack_f16_pair(Ba.z, Ba.w), \
                            pack_f16_pair(Bb.x, Bb.y), pack_f16_pair(Bb.z, Bb.w)); \
    *(uint4*)(&As[buf][(size_t)ar * 40 + ak])        = _av0;                  \
    *(uint4*)(&As[buf][(size_t)(64 + ar) * 40 + ak]) = _av1;                  \
    uint4 _bl = make_uint4(dq_pair((unsigned)P[0].x), dq_pair((unsigned)P[1].x), \
                           dq_pair((unsigned)P[2].x), dq_pair((unsigned)P[3].x)); \
    uint4 _bh = make_uint4(dq_pair((unsigned)P[0].y), dq_pair((unsigned)P[1].y), \
                           dq_pair((unsigned)P[2].y), dq_pair((unsigned)P[3].y)); \
    *(uint4*)(&Bs[buf][(size_t)nl * 40 + rg * 8])       = _bl;                \
    *(uint4*)(&Bs[buf][(size_t)(nl + 1) * 40 + rg * 8]) = _bh;                \
} while (0)

#define MFMA_STEP(buf) do {                                                   \
    f16x8 _af[4], _bf[4];                                                     \
    _Pragma("unroll")                                                         \
    for (int mi = 0; mi < 4; ++mi)                                            \
        _af[mi] = *(const f16x8*)&As[buf][(size_t)(wr * 64 + mi * 16 + lr) * 40 + lq * 8]; \
    _Pragma("unroll")                                                         \
    for (int ni = 0; ni < 4; ++ni)                                            \
        _bf[ni] = *(const f16x8*)&Bs[buf][(size_t)(wc * 64 + ni * 16 + lr) * 40 + lq * 8]; \
    _Pragma("unroll")                                                         \
    for (int mi = 0; mi < 4; ++mi)                                            \
        _Pragma("unroll")                                                     \
        for (int ni = 0; ni < 4; ++ni)                                        \
            acc[mi][ni] = __builtin_amdgcn_mfma_f32_16x16x32_f16(             \
                _af[mi], _bf[ni], acc[mi][ni], 0, 0, 0);                      \
} while (0)

    // ---- prologue ----
    LOAD_SET(sA0a, sA0b, sA1a, sA1b, sP0, 0);
    WRITE_SET(sA0a, sA0b, sA1a, sA1b, sP0, 0);
    LOAD_SET(tA0a, tA0b, tA1a, tA1b, tP0, 1);
    __syncthreads();

    // ---- main loop: steps 0..125, unrolled x2 (static buffers/sets) ----
    for (int kt = 0; kt < NT - 2; kt += 2) {
        // step kt (even, cur=0): MFMA buf0; write set1 (kt+1) -> buf1; load set0 <- kt+2
        MFMA_STEP(0);
        WRITE_SET(tA0a, tA0b, tA1a, tA1b, tP0, 1);
        LOAD_SET(sA0a, sA0b, sA1a, sA1b, sP0, kt + 2);
        __syncthreads();
        // step kt+1 (odd, cur=1): MFMA buf1; write set0 (kt+2) -> buf0; load set1 <- kt+3
        MFMA_STEP(1);
        WRITE_SET(sA0a, sA0b, sA1a, sA1b, sP0, 0);
        LOAD_SET(tA0a, tA0b, tA1a, tA1b, tP0, kt + 3);
        __syncthreads();
    }
    // step 126 (cur=0): MFMA buf0; write set1 (data 127) -> buf1
    MFMA_STEP(0);
    WRITE_SET(tA0a, tA0b, tA1a, tA1b, tP0, 1);
    __syncthreads();
    // step 127 (cur=1)
    MFMA_STEP(1);

    // ---- epilogue: per-column scale, f32 store ----
#pragma unroll
    for (int ni = 0; ni < 4; ++ni) {
        const int col = bn0 + wc * 64 + ni * 16 + lr;
        const float s = WS[col];
#pragma unroll
        for (int mi = 0; mi < 4; ++mi) {
            const int row = bm0 + wr * 64 + mi * 16 + lq * 4;
#pragma unroll
            for (int i = 0; i < 4; ++i) {
                Out[(size_t)(row + i) * N_DIM + col] = acc[mi][ni][i] * s;
            }
        }
    }
}

extern "C" void kernel_launch(void* const* d_in, const int* in_sizes, int n_in,
                              void* d_out, int out_size, void* d_ws, size_t ws_size,
                              hipStream_t stream) {
    const float* X  = (const float*)d_in[0];
    const int*   WP = (const int*)d_in[1];
    const float* WS = (const float*)d_in[2];
    float*       Out = (float*)d_out;

    dim3 grid((N_DIM / 128) * (M_DIM / 128));   // 86 * 32 = 2752
    qgemm_kernel<<<grid, 256, 0, stream>>>(X, WP, WS, Out);
}